// Round 3
// baseline (182.714 us; speedup 1.0000x reference)
//
#include <hip/hip_runtime.h>

// DifferentiableProjectionLayer: 262144 independent rows of 64 assets,
// 20 iters of {box clip + simplex shift + 8 disjoint group projections}.
//
// Mapping: ONE ROW PER LANE. w[64] lives in VGPRs; all sums are lane-local
// trees (no cross-lane ops). Groups (asset j in group j%8) are projected
// in parallel from 8 group partial sums. Group bounds sit in SGPRs.
//
// Fast path (verified at runtime, wave-uniform): A is the structural one-hot
// matrix (A[g][j] == (j%8==g)), box bounds uniform with lb<=ub. Then
// ns=8, sumA=8, dot(a,w)=group sum, clip = v_med3. eps=1e-9 vanishes in f32
// so the group math is exact. Generic fallback reloads params from cache
// each iteration (never taken on this data; keeps fast-path VGPRs low).

#define NA 64
#define NG 8

__global__ __launch_bounds__(256) void proj_kernel(
    const float* __restrict__ x,
    const float* __restrict__ box_lb,
    const float* __restrict__ box_ub,
    const float* __restrict__ group_A,
    const float* __restrict__ group_lb,
    const float* __restrict__ group_ub,
    const int*  __restrict__ num_iter,
    float* __restrict__ out,
    int nrows)
{
    const int r = blockIdx.x * blockDim.x + threadIdx.x;
    if (r >= nrows) return;

    const float* __restrict__ xr = x + (size_t)r * NA;
    float* __restrict__ outr = out + (size_t)r * NA;

    float w[NA];
#pragma unroll
    for (int q = 0; q < NA / 4; ++q) {
        const float4 v = reinterpret_cast<const float4*>(xr)[q];
        w[4 * q + 0] = v.x; w[4 * q + 1] = v.y;
        w[4 * q + 2] = v.z; w[4 * q + 3] = v.w;
    }

    const int iters = *num_iter;

    // group bounds: uniform -> SGPRs
    float glb_s[NG], gub_s[NG];
#pragma unroll
    for (int g = 0; g < NG; ++g) { glb_s[g] = group_lb[g]; gub_s[g] = group_ub[g]; }

    // ---- fast-path validity check (wave-uniform data) ----
    const int l = threadIdx.x & 63;
    const float lb0 = box_lb[0], ub0 = box_ub[0];
    bool ok = (box_lb[l] == lb0) && (box_ub[l] == ub0) && (lb0 <= ub0);
#pragma unroll
    for (int g = 0; g < NG; ++g) {
        const float expect = ((l & 7) == g) ? 1.0f : 0.0f;
        ok = ok && (group_A[g * NA + l] == expect);
    }

    if (__all(ok)) {
        // ================= FAST PATH =================
        // ns = 8, sumA = 8; 8 + 1e-9 rounds to 8.0f so inv = 0.125 exactly.
        const float inv8 = 1.0f / (8.0f + 1e-9f);       // == 0.125f
        const float scale = 8.0f * inv8;                // == 1.0f

        for (int it = 0; it < iters; ++it) {
            // box clip (med3: lb<=ub verified)
#pragma unroll
            for (int j = 0; j < NA; ++j)
                w[j] = __builtin_amdgcn_fmed3f(w[j], lb0, ub0);

            // 8 group sums + row sum (lane-local trees)
            float gs[NG];
#pragma unroll
            for (int g = 0; g < NG; ++g) {
                const float a = w[g] + w[g + 8], b = w[g + 16] + w[g + 24];
                const float c = w[g + 32] + w[g + 40], d = w[g + 48] + w[g + 56];
                gs[g] = (a + b) + (c + d);
            }
            const float S = ((gs[0] + gs[1]) + (gs[2] + gs[3]))
                          + ((gs[4] + gs[5]) + (gs[6] + gs[7]));
            const float shift = (S - 1.0f) * (1.0f / NA);

            // all 8 group projections in parallel
            float u[NG];
#pragma unroll
            for (int g = 0; g < NG; ++g) {
                const float Aw  = fmaf(-8.0f, shift, gs[g]);  // dot after box shift
                const float e1  = fmaxf(Aw - gub_s[g], 0.0f);
                const float Aw2 = fmaf(-scale, e1, Aw);       // analytic recompute
                const float e2  = fminf(Aw2 - glb_s[g], 0.0f);
                u[g] = fmaf(e1 + e2, inv8, shift);
            }
            // fused update: w -= shift + d_g
#pragma unroll
            for (int k = 0; k < 8; ++k)
#pragma unroll
                for (int g = 0; g < NG; ++g)
                    w[8 * k + g] -= u[g];
        }
        // final box_simplex
        float S = 0.0f;
        {
            float ps[NG];
#pragma unroll
            for (int g = 0; g < NG; ++g) {
                w[g]      = __builtin_amdgcn_fmed3f(w[g], lb0, ub0);
                ps[g] = w[g];
            }
#pragma unroll
            for (int j = NG; j < NA; ++j) {
                w[j] = __builtin_amdgcn_fmed3f(w[j], lb0, ub0);
                ps[j & 7] += w[j];
            }
            S = ((ps[0] + ps[1]) + (ps[2] + ps[3])) + ((ps[4] + ps[5]) + (ps[6] + ps[7]));
        }
        const float shift = (S - 1.0f) * (1.0f / NA);
#pragma unroll
        for (int j = 0; j < NA; ++j) w[j] -= shift;
    } else {
        // ================= GENERIC PATH =================
        // Faithful sequential Dykstra; reloads params from cache each iter
        // (keeps fast-path register pressure unaffected; never taken here).
        for (int it = 0; it < iters; ++it) {
            float S = 0.0f;
#pragma unroll
            for (int j = 0; j < NA; ++j) {
                w[j] = fminf(fmaxf(w[j], box_lb[j]), box_ub[j]);
                S += w[j];
            }
            const float shift = (S - 1.0f) * (1.0f / NA);
#pragma unroll
            for (int j = 0; j < NA; ++j) w[j] -= shift;

            for (int g = 0; g < NG; ++g) {          // sequential groups
                const float* __restrict__ a = group_A + g * NA;
                float ns = 0.0f, Aw = 0.0f;
#pragma unroll
                for (int j = 0; j < NA; ++j) {
                    const float av = a[j];
                    ns = fmaf(av, av, ns);
                    Aw = fmaf(av, w[j], Aw);
                }
                const float invg = 1.0f / (ns + 1e-9f);
                const float d1 = (Aw > gub_s[g]) ? (Aw - gub_s[g]) * invg : 0.0f;
#pragma unroll
                for (int j = 0; j < NA; ++j) w[j] = fmaf(-d1, a[j], w[j]);
                float Aw2 = 0.0f;
#pragma unroll
                for (int j = 0; j < NA; ++j) Aw2 = fmaf(a[j], w[j], Aw2);
                const float d2 = (Aw2 < glb_s[g]) ? (Aw2 - glb_s[g]) * invg : 0.0f;
#pragma unroll
                for (int j = 0; j < NA; ++j) w[j] = fmaf(-d2, a[j], w[j]);
            }
        }
        float S = 0.0f;
#pragma unroll
        for (int j = 0; j < NA; ++j) {
            w[j] = fminf(fmaxf(w[j], box_lb[j]), box_ub[j]);
            S += w[j];
        }
        const float shift = (S - 1.0f) * (1.0f / NA);
#pragma unroll
        for (int j = 0; j < NA; ++j) w[j] -= shift;
    }

    // store
#pragma unroll
    for (int q = 0; q < NA / 4; ++q) {
        float4 v;
        v.x = w[4 * q + 0]; v.y = w[4 * q + 1];
        v.z = w[4 * q + 2]; v.w = w[4 * q + 3];
        reinterpret_cast<float4*>(outr)[q] = v;
    }
}

extern "C" void kernel_launch(void* const* d_in, const int* in_sizes, int n_in,
                              void* d_out, int out_size, void* d_ws, size_t ws_size,
                              hipStream_t stream) {
    const float* x        = (const float*)d_in[0];
    const float* box_lb   = (const float*)d_in[1];
    const float* box_ub   = (const float*)d_in[2];
    const float* group_A  = (const float*)d_in[3];
    const float* group_lb = (const float*)d_in[4];
    const float* group_ub = (const float*)d_in[5];
    const int*   num_iter = (const int*)d_in[6];
    float* out = (float*)d_out;

    const int nrows = in_sizes[0] / NA;          // 262144
    const int block = 256;                       // one row per thread
    const int grid = (nrows + block - 1) / block;

    proj_kernel<<<grid, block, 0, stream>>>(x, box_lb, box_ub, group_A,
                                            group_lb, group_ub, num_iter,
                                            out, nrows);
}

// Round 4
// 150.699 us; speedup vs baseline: 1.2124x; 1.2124x over previous
//
#include <hip/hip_runtime.h>

// DifferentiableProjectionLayer: 262144 independent rows of 64 assets,
// 20 iters of {box clip + simplex shift + 8 disjoint group projections}.
//
// Structure: ONE ROW PER LANE, w[64] in VGPRs, zero cross-lane ops.
// Two kernels to keep register allocation clean (R3 lesson: sharing w[]
// between fast and generic paths in one kernel forced a spill):
//   proj_fast    - structural one-hot A + uniform box bounds (this data).
//                  __launch_bounds__(256,4) => 128 VGPR budget, needs ~90.
//   proj_generic - faithful general Dykstra fallback; early-exits when the
//                  fast kernel handled it. Never does work on this data.
// Both are launched every call; exactly one writes d_out. Wave-uniform
// device-side check => deterministic, graph-capture safe.

#define NA 64
#define NG 8

__device__ __forceinline__ bool structural_ok(const float* __restrict__ box_lb,
                                              const float* __restrict__ box_ub,
                                              const float* __restrict__ group_A,
                                              int l) {
    const float lb0 = box_lb[0], ub0 = box_ub[0];
    bool ok = (box_lb[l] == lb0) && (box_ub[l] == ub0) && (lb0 <= ub0);
#pragma unroll
    for (int g = 0; g < NG; ++g) {
        const float expect = ((l & 7) == g) ? 1.0f : 0.0f;
        ok = ok && (group_A[g * NA + l] == expect);
    }
    return __all(ok);
}

__global__ __launch_bounds__(256, 4) void proj_fast(
    const float* __restrict__ x,
    const float* __restrict__ box_lb,
    const float* __restrict__ box_ub,
    const float* __restrict__ group_A,
    const float* __restrict__ group_lb,
    const float* __restrict__ group_ub,
    const int*  __restrict__ num_iter,
    float* __restrict__ out,
    int nrows)
{
    if (!structural_ok(box_lb, box_ub, group_A, threadIdx.x & 63)) return;

    const int r = blockIdx.x * blockDim.x + threadIdx.x;
    if (r >= nrows) return;

    const float* __restrict__ xr = x + (size_t)r * NA;
    float* __restrict__ outr = out + (size_t)r * NA;

    float w[NA];
#pragma unroll
    for (int q = 0; q < NA / 4; ++q) {
        const float4 v = reinterpret_cast<const float4*>(xr)[q];
        w[4 * q + 0] = v.x; w[4 * q + 1] = v.y;
        w[4 * q + 2] = v.z; w[4 * q + 3] = v.w;
    }

    const float lb0 = box_lb[0], ub0 = box_ub[0];   // uniform -> SGPR
    float glb_s[NG], gub_s[NG];                      // uniform -> SGPR
#pragma unroll
    for (int g = 0; g < NG; ++g) { glb_s[g] = group_lb[g]; gub_s[g] = group_ub[g]; }

    const int iters = *num_iter;

    // ns = 8, sumA = 8; 8+1e-9 rounds to 8.0f so inv = 0.125 exactly and the
    // analytic second-dot recompute (Aw2 = Aw - e1) is bit-exact vs reference.
    const float inv8 = 1.0f / (8.0f + 1e-9f);        // == 0.125f
    const float scale = 8.0f * inv8;                 // == 1.0f

    for (int it = 0; it < iters; ++it) {
#pragma unroll
        for (int j = 0; j < NA; ++j)
            w[j] = __builtin_amdgcn_fmed3f(w[j], lb0, ub0);

        float gs[NG];
#pragma unroll
        for (int g = 0; g < NG; ++g) {
            const float a = w[g] + w[g + 8], b = w[g + 16] + w[g + 24];
            const float c = w[g + 32] + w[g + 40], d = w[g + 48] + w[g + 56];
            gs[g] = (a + b) + (c + d);
        }
        const float S = ((gs[0] + gs[1]) + (gs[2] + gs[3]))
                      + ((gs[4] + gs[5]) + (gs[6] + gs[7]));
        const float shift = (S - 1.0f) * (1.0f / NA);

        float u[NG];
#pragma unroll
        for (int g = 0; g < NG; ++g) {
            const float Aw  = fmaf(-8.0f, shift, gs[g]);
            const float e1  = fmaxf(Aw - gub_s[g], 0.0f);
            const float Aw2 = fmaf(-scale, e1, Aw);
            const float e2  = fminf(Aw2 - glb_s[g], 0.0f);
            u[g] = fmaf(e1 + e2, inv8, shift);
        }
#pragma unroll
        for (int k = 0; k < 8; ++k)
#pragma unroll
            for (int g = 0; g < NG; ++g)
                w[8 * k + g] -= u[g];
    }

    // final box_simplex
    float ps[NG];
#pragma unroll
    for (int g = 0; g < NG; ++g) {
        w[g] = __builtin_amdgcn_fmed3f(w[g], lb0, ub0);
        ps[g] = w[g];
    }
#pragma unroll
    for (int j = NG; j < NA; ++j) {
        w[j] = __builtin_amdgcn_fmed3f(w[j], lb0, ub0);
        ps[j & 7] += w[j];
    }
    const float S = ((ps[0] + ps[1]) + (ps[2] + ps[3]))
                  + ((ps[4] + ps[5]) + (ps[6] + ps[7]));
    const float shift = (S - 1.0f) * (1.0f / NA);

#pragma unroll
    for (int q = 0; q < NA / 4; ++q) {
        float4 v;
        v.x = w[4 * q + 0] - shift; v.y = w[4 * q + 1] - shift;
        v.z = w[4 * q + 2] - shift; v.w = w[4 * q + 3] - shift;
        reinterpret_cast<float4*>(outr)[q] = v;
    }
}

__global__ __launch_bounds__(256) void proj_generic(
    const float* __restrict__ x,
    const float* __restrict__ box_lb,
    const float* __restrict__ box_ub,
    const float* __restrict__ group_A,
    const float* __restrict__ group_lb,
    const float* __restrict__ group_ub,
    const int*  __restrict__ num_iter,
    float* __restrict__ out,
    int nrows)
{
    if (structural_ok(box_lb, box_ub, group_A, threadIdx.x & 63)) return; // fast kernel handled it

    const int r = blockIdx.x * blockDim.x + threadIdx.x;
    if (r >= nrows) return;

    const float* __restrict__ xr = x + (size_t)r * NA;
    float* __restrict__ outr = out + (size_t)r * NA;

    float w[NA];
#pragma unroll
    for (int j = 0; j < NA; ++j) w[j] = xr[j];

    const int iters = *num_iter;

    for (int it = 0; it < iters; ++it) {
        float S = 0.0f;
#pragma unroll
        for (int j = 0; j < NA; ++j) {
            w[j] = fminf(fmaxf(w[j], box_lb[j]), box_ub[j]);
            S += w[j];
        }
        const float shift = (S - 1.0f) * (1.0f / NA);
#pragma unroll
        for (int j = 0; j < NA; ++j) w[j] -= shift;

        for (int g = 0; g < NG; ++g) {              // sequential groups
            const float* __restrict__ a = group_A + g * NA;
            float ns = 0.0f, Aw = 0.0f;
#pragma unroll
            for (int j = 0; j < NA; ++j) {
                const float av = a[j];
                ns = fmaf(av, av, ns);
                Aw = fmaf(av, w[j], Aw);
            }
            const float invg = 1.0f / (ns + 1e-9f);
            const float gub = group_ub[g], glb = group_lb[g];
            const float d1 = (Aw > gub) ? (Aw - gub) * invg : 0.0f;
#pragma unroll
            for (int j = 0; j < NA; ++j) w[j] = fmaf(-d1, a[j], w[j]);
            float Aw2 = 0.0f;
#pragma unroll
            for (int j = 0; j < NA; ++j) Aw2 = fmaf(a[j], w[j], Aw2);
            const float d2 = (Aw2 < glb) ? (Aw2 - glb) * invg : 0.0f;
#pragma unroll
            for (int j = 0; j < NA; ++j) w[j] = fmaf(-d2, a[j], w[j]);
        }
    }
    float S = 0.0f;
#pragma unroll
    for (int j = 0; j < NA; ++j) {
        w[j] = fminf(fmaxf(w[j], box_lb[j]), box_ub[j]);
        S += w[j];
    }
    const float shift = (S - 1.0f) * (1.0f / NA);
#pragma unroll
    for (int j = 0; j < NA; ++j) outr[j] = w[j] - shift;
}

extern "C" void kernel_launch(void* const* d_in, const int* in_sizes, int n_in,
                              void* d_out, int out_size, void* d_ws, size_t ws_size,
                              hipStream_t stream) {
    const float* x        = (const float*)d_in[0];
    const float* box_lb   = (const float*)d_in[1];
    const float* box_ub   = (const float*)d_in[2];
    const float* group_A  = (const float*)d_in[3];
    const float* group_lb = (const float*)d_in[4];
    const float* group_ub = (const float*)d_in[5];
    const int*   num_iter = (const int*)d_in[6];
    float* out = (float*)d_out;

    const int nrows = in_sizes[0] / NA;          // 262144
    const int block = 256;                       // one row per thread
    const int grid = (nrows + block - 1) / block;

    proj_fast<<<grid, block, 0, stream>>>(x, box_lb, box_ub, group_A,
                                          group_lb, group_ub, num_iter,
                                          out, nrows);
    proj_generic<<<grid, block, 0, stream>>>(x, box_lb, box_ub, group_A,
                                             group_lb, group_ub, num_iter,
                                             out, nrows);
}